// Round 3
// baseline (1034.727 us; speedup 1.0000x reference)
//
#include <hip/hip_runtime.h>

#define LMAX  10
#define BATCH 16384
#define NCOLS 381
#define NF    121   // sum over l of (2l+1)

// ---------------------------------------------------------------------------
// Triple decode: output column t -> (l1, l2, l, cg offset). Wave-uniform.
// ---------------------------------------------------------------------------
__device__ __forceinline__ void decode_triple(int t, int& l1, int& l2, int& l, int& off)
{
    int tt = t, o = 0;
    for (int a = 0; a <= LMAX; ++a) {
        for (int bq = a; bq <= LMAX; ++bq) {
            const int d    = (2 * a + 1) * (2 * bq + 1);
            const int lmin = bq - a;
            const int lmx  = (a + bq < LMAX) ? (a + bq) : LMAX;
            const int cnt  = lmx - lmin + 1;
            if (tt < cnt) { l1 = a; l2 = bq; l = lmin + tt; off = o; return; }
            tt -= cnt; o += d * d;
        }
    }
    l1 = l2 = l = off = 0;
}

// f[l][m], m = j - l, from packed (11,11) coeff rows.
__device__ __forceinline__ float2 load_direct(const float* __restrict__ crow,
                                              const float* __restrict__ cirow,
                                              int l, int j)
{
    const int m = j - l;
    if (m >= 0) return make_float2(crow[m], cirow[m]);
    const int a = -m;
    const float sg = (a & 1) ? -1.0f : 1.0f;
    return make_float2(sg * crow[a], -sg * cirow[a]);
}

// ---------------------------------------------------------------------------
// Core contraction for one (l1,l2,l) triple, one batch element.
// Returns complex result (re, im).
// ---------------------------------------------------------------------------
template<int L, class G1, class G2, class GL>
__device__ __forceinline__ float2 core(G1 g1, G2 g2, GL gl,
                                       const float* __restrict__ cgp,
                                       int d1, int d2, int d)
{
    constexpr int W = 2 * L + 1;
    float accr[W], acci[W];
#pragma unroll
    for (int k = 0; k < W; ++k) { accr[k] = 0.f; acci[k] = 0.f; }

    for (int m1 = 0; m1 < d1; ++m1) {
        const float2 a = g1(m1);
        const float* rowbase = cgp + (size_t)m1 * d2 * d;
        for (int m2 = 0; m2 < d2; ++m2) {
            const float2 bb = g2(m2);
            const float tr = a.x * bb.x - a.y * bb.y;
            const float ti = a.x * bb.y + a.y * bb.x;
            const float* row = rowbase + (size_t)m2 * d;   // wave-uniform addr
#pragma unroll
            for (int k = 0; k < W; ++k) {
                const float c = row[k];
                accr[k] = fmaf(tr, c, accr[k]);
                acci[k] = fmaf(ti, c, acci[k]);
            }
        }
    }

    float orr = 0.f, oii = 0.f;
#pragma unroll
    for (int k = 0; k < W; ++k) {
        const float2 fl = gl(k);
        orr = fmaf(accr[k], fl.x, fmaf( acci[k], fl.y, orr));
        oii = fmaf(acci[k], fl.x, fmaf(-accr[k], fl.y, oii));
    }
    return make_float2(orr, oii);
}

#define L_SWITCH(RESULT, CALL)                      \
    switch (l) {                                    \
        case 0:  RESULT = CALL(0);  break;          \
        case 1:  RESULT = CALL(1);  break;          \
        case 2:  RESULT = CALL(2);  break;          \
        case 3:  RESULT = CALL(3);  break;          \
        case 4:  RESULT = CALL(4);  break;          \
        case 5:  RESULT = CALL(5);  break;          \
        case 6:  RESULT = CALL(6);  break;          \
        case 7:  RESULT = CALL(7);  break;          \
        case 8:  RESULT = CALL(8);  break;          \
        case 9:  RESULT = CALL(9);  break;          \
        default: RESULT = CALL(10); break;          \
    }

// ---------------------------------------------------------------------------
// Kernel 1 (planes path): expand coeffs into f planes, layout (121, B) float2.
// ---------------------------------------------------------------------------
__global__ __launch_bounds__(256) void build_f(const float* __restrict__ cre,
                                               const float* __restrict__ cim,
                                               float2* __restrict__ f)
{
    const int b   = blockIdx.x * blockDim.x + threadIdx.x;
    const int idx = blockIdx.y;                              // 0..120
    int l = (int)sqrtf((float)idx + 0.5f);
    if (l * l > idx) --l;
    if ((l + 1) * (l + 1) <= idx) ++l;
    const int j = idx - l * l;                               // 0..2l
    const float2 v = load_direct(cre + (size_t)b * 121 + l * 11,
                                 cim + (size_t)b * 121 + l * 11, l, j);
    f[(size_t)idx * BATCH + b] = v;
}

// ---------------------------------------------------------------------------
// Kernel 2 (planes path): contraction reading coalesced f planes.
// MODE 0: real-only output, float at b*NCOLS+t  (out_size == B*NCOLS)
// MODE 1: interleaved complex, float2 at b*NCOLS+t (out_size == 2*B*NCOLS)
// ---------------------------------------------------------------------------
template<int MODE>
__global__ __launch_bounds__(256) void so3_tp_planes(const float2* __restrict__ f,
                                                     const float* __restrict__ cg,
                                                     float* __restrict__ out,
                                                     long long out_floats)
{
    const int b = blockIdx.x * blockDim.x + threadIdx.x;
    const int t = blockIdx.y;
    int l1, l2, l, off;
    decode_triple(t, l1, l2, l, off);
    const int d1 = 2 * l1 + 1, d2 = 2 * l2 + 1, d = d1 * d2;
    const int lmin = l2 - l1;
    const int s = l * l - lmin * lmin;

    const float2* f1p = f + (size_t)(l1 * l1) * BATCH + b;
    const float2* f2p = f + (size_t)(l2 * l2) * BATCH + b;
    const float2* flp = f + (size_t)(l  * l ) * BATCH + b;
    const float*  cgp = cg + (size_t)off + s;

    auto g1 = [&](int j) { return f1p[(size_t)j * BATCH]; };
    auto g2 = [&](int j) { return f2p[(size_t)j * BATCH]; };
    auto gl = [&](int j) { return flp[(size_t)j * BATCH]; };

    float2 r;
#define CALL_CORE(LL) core<LL>(g1, g2, gl, cgp, d1, d2, d)
    L_SWITCH(r, CALL_CORE)
#undef CALL_CORE

    const long long oi = (long long)b * NCOLS + t;
    if (MODE == 0) {
        if (oi < out_floats) out[oi] = r.x;
    } else {
        if ((oi + 1) * 2 <= out_floats) ((float2*)out)[oi] = r;
    }
}

// ---------------------------------------------------------------------------
// Fused path (no workspace): loads f fragments straight from cre/cim.
// ---------------------------------------------------------------------------
template<int MODE>
__global__ __launch_bounds__(256) void so3_tp_direct(const float* __restrict__ cre,
                                                     const float* __restrict__ cim,
                                                     const float* __restrict__ cg,
                                                     float* __restrict__ out,
                                                     long long out_floats)
{
    const int b = blockIdx.x * blockDim.x + threadIdx.x;
    const int t = blockIdx.y;
    int l1, l2, l, off;
    decode_triple(t, l1, l2, l, off);
    const int d1 = 2 * l1 + 1, d2 = 2 * l2 + 1, d = d1 * d2;
    const int lmin = l2 - l1;
    const int s = l * l - lmin * lmin;

    const float* cr = cre + (size_t)b * 121;
    const float* ci = cim + (size_t)b * 121;
    const float* crow1 = cr + l1 * 11; const float* cirow1 = ci + l1 * 11;
    const float* crow2 = cr + l2 * 11; const float* cirow2 = ci + l2 * 11;
    const float* crowl = cr + l  * 11; const float* cirowl = ci + l  * 11;
    const float*  cgp  = cg + (size_t)off + s;

    auto g1 = [&](int j) { return load_direct(crow1, cirow1, l1, j); };
    auto g2 = [&](int j) { return load_direct(crow2, cirow2, l2, j); };
    auto gl = [&](int j) { return load_direct(crowl, cirowl, l,  j); };

    float2 r;
#define CALL_CORE(LL) core<LL>(g1, g2, gl, cgp, d1, d2, d)
    L_SWITCH(r, CALL_CORE)
#undef CALL_CORE

    const long long oi = (long long)b * NCOLS + t;
    if (MODE == 0) {
        if (oi < out_floats) out[oi] = r.x;
    } else {
        if ((oi + 1) * 2 <= out_floats) ((float2*)out)[oi] = r;
    }
}

extern "C" void kernel_launch(void* const* d_in, const int* in_sizes, int n_in,
                              void* d_out, int out_size, void* d_ws, size_t ws_size,
                              hipStream_t stream)
{
    const float* cre = (const float*)d_in[0];   // (B, 11, 11)
    const float* cim = (const float*)d_in[1];   // (B, 11, 11)
    const float* cg  = (const float*)d_in[2];   // (total,)
    float* out = (float*)d_out;
    const long long out_floats = (long long)out_size;

    // Layout hypothesis dispatch:
    //   out_size == B*NCOLS      -> complex64 ref was astype(float32): REAL PART ONLY
    //   out_size == 2*B*NCOLS    -> complex64 viewed as float32: interleaved (re,im)
    const bool real_only = (out_size <= (long long)BATCH * NCOLS);

    const size_t f_bytes = (size_t)NF * BATCH * sizeof(float2);  // 15.86 MB
    const dim3 grid(BATCH / 256, NCOLS);

    if (ws_size >= f_bytes) {
        float2* f = (float2*)d_ws;
        build_f<<<dim3(BATCH / 256, NF), 256, 0, stream>>>(cre, cim, f);
        if (real_only) so3_tp_planes<0><<<grid, 256, 0, stream>>>(f, cg, out, out_floats);
        else           so3_tp_planes<1><<<grid, 256, 0, stream>>>(f, cg, out, out_floats);
    } else {
        if (real_only) so3_tp_direct<0><<<grid, 256, 0, stream>>>(cre, cim, cg, out, out_floats);
        else           so3_tp_direct<1><<<grid, 256, 0, stream>>>(cre, cim, cg, out, out_floats);
    }
}

// Round 5
// 699.120 us; speedup vs baseline: 1.4800x; 1.4800x over previous
//
#include <hip/hip_runtime.h>

#define LMAX   10
#define BATCH  16384
#define NCOLS  381
#define NF     121
#define NPAIRS 66

typedef __attribute__((ext_vector_type(8))) short    short8;
typedef __attribute__((ext_vector_type(8))) _Float16 half8;
typedef __attribute__((ext_vector_type(4))) float    floatx4;

__device__ __forceinline__ short f32_to_f16_bits(float x) {
    return __builtin_bit_cast(short, (_Float16)x);
}

// pair index p -> (l1, l2, cg offset, first output column)
__device__ __forceinline__ void decode_pair(int p, int& l1, int& l2,
                                            long long& off, int& colbase)
{
    long long o = 0; int cb = 0, idx = 0;
    for (int a = 0; a <= LMAX; ++a) {
        for (int bq = a; bq <= LMAX; ++bq) {
            const int d    = (2*a+1)*(2*bq+1);
            const int lmin = bq - a;
            const int lmx  = (a + bq < LMAX) ? (a + bq) : LMAX;
            if (idx == p) { l1 = a; l2 = bq; off = o; colbase = cb; return; }
            o += (long long)d * d; cb += lmx - lmin + 1; ++idx;
        }
    }
    l1 = l2 = 0; off = 0; colbase = 0;
}

// ---------------------------------------------------------------------------
// Kernel 1: expand coeffs into f planes, layout (121, BATCH) float2 (fp32).
// Verified correct in round 3.
// ---------------------------------------------------------------------------
__global__ __launch_bounds__(256) void build_f(const float* __restrict__ cre,
                                               const float* __restrict__ cim,
                                               float2* __restrict__ f)
{
    const int b   = blockIdx.x * blockDim.x + threadIdx.x;
    const int idx = blockIdx.y;                              // 0..120
    int l = (int)sqrtf((float)idx + 0.5f);
    if (l * l > idx) --l;
    if ((l + 1) * (l + 1) <= idx) ++l;
    const int j = idx - l * l;
    const int m = j - l;
    const float* crow  = cre + (size_t)b * 121 + l * 11;
    const float* cirow = cim + (size_t)b * 121 + l * 11;
    float re, im;
    if (m >= 0) { re = crow[m]; im = cirow[m]; }
    else {
        const int a = -m;
        const float sg = (a & 1) ? -1.0f : 1.0f;
        re = sg * crow[a]; im = -sg * cirow[a];
    }
    f[(size_t)idx * BATCH + b] = make_float2(re, im);
}

// ---------------------------------------------------------------------------
// MFMA pair kernel. Block = one (l1,l2) pair x 64 batch rows, 256 threads.
// f16 operands; T kept fp32 via two-pass (re, im) epilogue through LDS.
// LDS: staging A_re[64][40] + A_im[64][40] + B[128][40] f16 (20.5 KB)
//      unioned with T[64][131] fp32 (33.5 KB).
// ---------------------------------------------------------------------------
template<int NT>
__device__ __forceinline__ void pair_body(const float2* __restrict__ f,
                                          const float* __restrict__ cg,
                                          float* __restrict__ out,
                                          short* smem, int btile,
                                          int l1, int l2, long long off, int colbase)
{
    const int d1 = 2*l1 + 1, d2 = 2*l2 + 1, d = d1 * d2;
    const int lmin = l2 - l1;
    const int lmx  = (l1 + l2 < LMAX) ? (l1 + l2) : LMAX;
    const int used = (lmx+1)*(lmx+1) - lmin*lmin;
    const int n_l  = lmx - lmin + 1;
    const int q1 = l1*l1, q2 = l2*l2;

    const int tid  = threadIdx.x;
    const int lane = tid & 63;
    const int w    = tid >> 6;        // wave 0..3 -> M-tile
    const int quad = lane >> 4;
    const int r16  = lane & 15;

    short* A_re = smem;               // [64][40] f16 bits
    short* A_im = smem + 64*40;
    short* B_s  = smem + 128*40;      // [128][40] f16 bits

    floatx4 accR[NT], accI[NT];
#pragma unroll
    for (int i = 0; i < NT; ++i) {
        accR[i] = (floatx4)0.0f; accI[i] = (floatx4)0.0f;
    }

    const int npan = (d + 31) >> 5;
    for (int pan = 0; pan < npan; ++pan) {
        const int k0 = pan << 5;

        // ---- stage A: tp[b, kk] = f1[b,m1] * f2[b,m2] (complex), f16 ----
        {
            const int mi = tid & 63;
            const int kq = tid >> 6;          // 8-wide k group
            const int b  = btile + mi;
            int kk = k0 + kq * 8;
            int m1 = kk / d2;
            int m2 = kk - m1 * d2;
            short8 vr, vi;
#pragma unroll
            for (int j = 0; j < 8; ++j) {
                float tr = 0.f, ti = 0.f;
                if (kk < d) {
                    const float2 a = f[(size_t)(q1 + m1) * BATCH + b];
                    const float2 c = f[(size_t)(q2 + m2) * BATCH + b];
                    tr = a.x * c.x - a.y * c.y;
                    ti = a.x * c.y + a.y * c.x;
                }
                vr[j] = f32_to_f16_bits(tr);
                vi[j] = f32_to_f16_bits(ti);
                ++kk;
                if (++m2 == d2) { m2 = 0; ++m1; }
            }
            *(short8*)&A_re[mi * 40 + kq * 8] = vr;
            *(short8*)&A_im[mi * 40 + kq * 8] = vi;
        }

        // ---- stage B: cg[kk, n] f16, zero-padded ----
        {
            const int n  = tid & 127;
            const int kh = tid >> 7;          // 0..1 -> 16-wide k half
#pragma unroll
            for (int g = 0; g < 2; ++g) {
                const int kb = k0 + kh * 16 + g * 8;
                short8 vb;
#pragma unroll
                for (int j = 0; j < 8; ++j) {
                    const int kk = kb + j;
                    float v = 0.f;
                    if (kk < d && n < used) v = cg[off + (size_t)kk * d + n];
                    vb[j] = f32_to_f16_bits(v);
                }
                *(short8*)&B_s[n * 40 + kh * 16 + g * 8] = vb;
            }
        }
        __syncthreads();

        // ---- MFMA: A[m=lane&15][k=quad*8+j], B[k][n=lane&15] ----
        {
            const half8 are = __builtin_bit_cast(half8, *(const short8*)&A_re[(w*16 + r16) * 40 + quad * 8]);
            const half8 aim = __builtin_bit_cast(half8, *(const short8*)&A_im[(w*16 + r16) * 40 + quad * 8]);
#pragma unroll
            for (int n0 = 0; n0 < NT; ++n0) {
                const half8 bb = __builtin_bit_cast(half8, *(const short8*)&B_s[(n0*16 + r16) * 40 + quad * 8]);
                accR[n0] = __builtin_amdgcn_mfma_f32_16x16x32_f16(are, bb, accR[n0], 0, 0, 0);
                accI[n0] = __builtin_amdgcn_mfma_f32_16x16x32_f16(aim, bb, accI[n0], 0, 0, 0);
            }
        }
        __syncthreads();
    }

    // ---- two-pass fp32 epilogue; C/D: col=lane&15, row=quad*4+reg ----
    float* T = (float*)smem;                  // [64][131] fp32
    const int ntask = 64 * n_l;
    float part[3] = {0.f, 0.f, 0.f};

    // pass 1: real
#pragma unroll
    for (int n0 = 0; n0 < NT; ++n0)
#pragma unroll
        for (int r = 0; r < 4; ++r)
            T[(w*16 + quad*4 + r) * 131 + n0*16 + r16] = accR[n0][r];
    __syncthreads();
    {
        int it = 0;
        for (int task = tid; task < ntask; task += 256, ++it) {
            const int row = task & 63;
            const int li  = task >> 6;
            const int l   = lmin + li;
            const int sl  = l*l - lmin*lmin;
            const int W   = 2*l + 1;
            const int b   = btile + row;
            const float* Trow = T + row * 131 + sl;
            float acc = 0.f;
            for (int j = 0; j < W; ++j)
                acc = fmaf(Trow[j], f[(size_t)(l*l + j) * BATCH + b].x, acc);
            part[it] = acc;
        }
    }
    __syncthreads();

    // pass 2: imaginary
#pragma unroll
    for (int n0 = 0; n0 < NT; ++n0)
#pragma unroll
        for (int r = 0; r < 4; ++r)
            T[(w*16 + quad*4 + r) * 131 + n0*16 + r16] = accI[n0][r];
    __syncthreads();
    {
        int it = 0;
        for (int task = tid; task < ntask; task += 256, ++it) {
            const int row = task & 63;
            const int li  = task >> 6;
            const int l   = lmin + li;
            const int sl  = l*l - lmin*lmin;
            const int W   = 2*l + 1;
            const int b   = btile + row;
            const float* Trow = T + row * 131 + sl;
            float acc = part[it];
            for (int j = 0; j < W; ++j)
                acc = fmaf(Trow[j], f[(size_t)(l*l + j) * BATCH + b].y, acc);
            out[(size_t)b * NCOLS + colbase + li] = acc;
        }
    }
}

__global__ __launch_bounds__(256) void so3_mfma(const float2* __restrict__ f,
                                                const float* __restrict__ cg,
                                                float* __restrict__ out)
{
    __shared__ __align__(16) short smem[16768];   // 33.5 KB
    const int btile = blockIdx.x * 64;
    const int p     = blockIdx.y;
    int l1, l2, colbase; long long off;
    decode_pair(p, l1, l2, off, colbase);
    const int lmin = l2 - l1;
    const int lmx  = (l1 + l2 < LMAX) ? (l1 + l2) : LMAX;
    const int used = (lmx+1)*(lmx+1) - lmin*lmin;
    const int nt   = (used + 15) >> 4;
    switch (nt) {
        case 1: pair_body<1>(f, cg, out, smem, btile, l1, l2, off, colbase); break;
        case 2: pair_body<2>(f, cg, out, smem, btile, l1, l2, off, colbase); break;
        case 3: pair_body<3>(f, cg, out, smem, btile, l1, l2, off, colbase); break;
        case 4: pair_body<4>(f, cg, out, smem, btile, l1, l2, off, colbase); break;
        case 5: pair_body<5>(f, cg, out, smem, btile, l1, l2, off, colbase); break;
        case 6: pair_body<6>(f, cg, out, smem, btile, l1, l2, off, colbase); break;
        case 7: pair_body<7>(f, cg, out, smem, btile, l1, l2, off, colbase); break;
        default: pair_body<8>(f, cg, out, smem, btile, l1, l2, off, colbase); break;
    }
}

// ---------------------------------------------------------------------------
// Fallback (fp32 VALU, no workspace): known-good structure from round 3.
// ---------------------------------------------------------------------------
template<int L>
__device__ __forceinline__ float core_fb(const float2* f1v, const float2* f2v,
                                         const float2* flv,
                                         const float* __restrict__ cgp,
                                         int d1, int d2, int d)
{
    constexpr int W = 2*L + 1;
    float accr[W], acci[W];
#pragma unroll
    for (int k = 0; k < W; ++k) { accr[k] = 0.f; acci[k] = 0.f; }
    for (int m1 = 0; m1 < d1; ++m1) {
        const float2 a = f1v[m1];
        const float* rowbase = cgp + (size_t)m1 * d2 * d;
        for (int m2 = 0; m2 < d2; ++m2) {
            const float2 bb = f2v[m2];
            const float tr = a.x*bb.x - a.y*bb.y;
            const float ti = a.x*bb.y + a.y*bb.x;
            const float* row = rowbase + (size_t)m2 * d;
#pragma unroll
            for (int k = 0; k < W; ++k) {
                accr[k] = fmaf(tr, row[k], accr[k]);
                acci[k] = fmaf(ti, row[k], acci[k]);
            }
        }
    }
    float orr = 0.f;
#pragma unroll
    for (int k = 0; k < W; ++k)
        orr = fmaf(accr[k], flv[k].x, fmaf(acci[k], flv[k].y, orr));
    return orr;
}

__global__ __launch_bounds__(256) void so3_tp_direct(const float* __restrict__ cre,
                                                     const float* __restrict__ cim,
                                                     const float* __restrict__ cg,
                                                     float* __restrict__ out)
{
    const int b = blockIdx.x * blockDim.x + threadIdx.x;
    const int t = blockIdx.y;
    int l1 = 0, l2 = 0, l = 0; long long off = 0;
    {
        int tt = t; long long o = 0;
        bool found = false;
        for (int a = 0; a <= LMAX && !found; ++a)
            for (int bq = a; bq <= LMAX && !found; ++bq) {
                const int d = (2*a+1)*(2*bq+1);
                const int lmin = bq - a;
                const int lmx = (a+bq < LMAX) ? (a+bq) : LMAX;
                const int cnt = lmx - lmin + 1;
                if (tt < cnt) { l1 = a; l2 = bq; l = lmin + tt; off = o; found = true; }
                else { tt -= cnt; o += (long long)d*d; }
            }
    }
    const int d1 = 2*l1+1, d2 = 2*l2+1, d = d1*d2;
    const int lmin = l2 - l1;
    const int s = l*l - lmin*lmin;

    const float* cr = cre + (size_t)b * 121;
    const float* ci = cim + (size_t)b * 121;
    float2 f1v[21], f2v[21], flv[21];
    for (int j = 0; j <= 2*l1; ++j) {
        const int m = j - l1;
        if (m >= 0) f1v[j] = make_float2(cr[l1*11+m], ci[l1*11+m]);
        else { const int a2 = -m; const float sg = (a2&1)?-1.f:1.f;
               f1v[j] = make_float2(sg*cr[l1*11+a2], -sg*ci[l1*11+a2]); }
    }
    for (int j = 0; j <= 2*l2; ++j) {
        const int m = j - l2;
        if (m >= 0) f2v[j] = make_float2(cr[l2*11+m], ci[l2*11+m]);
        else { const int a2 = -m; const float sg = (a2&1)?-1.f:1.f;
               f2v[j] = make_float2(sg*cr[l2*11+a2], -sg*ci[l2*11+a2]); }
    }
    for (int j = 0; j <= 2*l; ++j) {
        const int m = j - l;
        if (m >= 0) flv[j] = make_float2(cr[l*11+m], ci[l*11+m]);
        else { const int a2 = -m; const float sg = (a2&1)?-1.f:1.f;
               flv[j] = make_float2(sg*cr[l*11+a2], -sg*ci[l*11+a2]); }
    }
    const float* cgp = cg + off + s;
    float r;
    switch (l) {
        case 0: r = core_fb<0>(f1v,f2v,flv,cgp,d1,d2,d); break;
        case 1: r = core_fb<1>(f1v,f2v,flv,cgp,d1,d2,d); break;
        case 2: r = core_fb<2>(f1v,f2v,flv,cgp,d1,d2,d); break;
        case 3: r = core_fb<3>(f1v,f2v,flv,cgp,d1,d2,d); break;
        case 4: r = core_fb<4>(f1v,f2v,flv,cgp,d1,d2,d); break;
        case 5: r = core_fb<5>(f1v,f2v,flv,cgp,d1,d2,d); break;
        case 6: r = core_fb<6>(f1v,f2v,flv,cgp,d1,d2,d); break;
        case 7: r = core_fb<7>(f1v,f2v,flv,cgp,d1,d2,d); break;
        case 8: r = core_fb<8>(f1v,f2v,flv,cgp,d1,d2,d); break;
        case 9: r = core_fb<9>(f1v,f2v,flv,cgp,d1,d2,d); break;
        default: r = core_fb<10>(f1v,f2v,flv,cgp,d1,d2,d); break;
    }
    out[(size_t)b * NCOLS + t] = r;
}

extern "C" void kernel_launch(void* const* d_in, const int* in_sizes, int n_in,
                              void* d_out, int out_size, void* d_ws, size_t ws_size,
                              hipStream_t stream)
{
    const float* cre = (const float*)d_in[0];
    const float* cim = (const float*)d_in[1];
    const float* cg  = (const float*)d_in[2];
    float* out = (float*)d_out;

    const size_t f_bytes = (size_t)NF * BATCH * sizeof(float2);  // 15.86 MB
    if (ws_size >= f_bytes) {
        float2* f = (float2*)d_ws;
        build_f<<<dim3(BATCH / 256, NF), 256, 0, stream>>>(cre, cim, f);
        so3_mfma<<<dim3(BATCH / 64, NPAIRS), 256, 0, stream>>>(f, cg, out);
    } else {
        so3_tp_direct<<<dim3(BATCH / 256, NCOLS), 256, 0, stream>>>(cre, cim, cg, out);
    }
}

// Round 7
// 441.630 us; speedup vs baseline: 2.3430x; 1.5830x over previous
//
#include <hip/hip_runtime.h>

#define LMAX   10
#define BATCH  16384
#define NCOLS  381
#define NF     121
#define NPAIRS 66

typedef __attribute__((ext_vector_type(8))) short    short8;
typedef __attribute__((ext_vector_type(8))) _Float16 half8;
typedef __attribute__((ext_vector_type(4))) float    floatx4;

__device__ __forceinline__ short f32_to_f16_bits(float x) {
    return __builtin_bit_cast(short, (_Float16)x);   // RNE, same as round 5
}

// pair index p -> (l1, l2, cg offset, first output column, cg16 offset)
__device__ __forceinline__ void decode_pair_ext(int p, int& l1, int& l2,
                                                long long& off, int& colbase,
                                                int& c16off)
{
    long long o = 0; int cb = 0, c16 = 0, idx = 0;
    for (int a = 0; a <= LMAX; ++a) {
        for (int bq = a; bq <= LMAX; ++bq) {
            const int d    = (2*a+1)*(2*bq+1);
            const int lmin = bq - a;
            const int lmx  = (a + bq < LMAX) ? (a + bq) : LMAX;
            const int used = (lmx+1)*(lmx+1) - lmin*lmin;
            const int npan = (d + 31) >> 5;
            const int nt   = (used + 15) >> 4;
            if (idx == p) { l1 = a; l2 = bq; off = o; colbase = cb; c16off = c16; return; }
            o += (long long)d * d; cb += lmx - lmin + 1;
            c16 += nt * 16 * npan * 32; ++idx;
        }
    }
    l1 = l2 = 0; off = 0; colbase = 0; c16off = 0;
}

// ---------------------------------------------------------------------------
// Kernel 1: expand coeffs into f planes, layout (121, BATCH) float2 (fp32).
// Verified (rounds 3/5).
// ---------------------------------------------------------------------------
__global__ __launch_bounds__(256) void build_f(const float* __restrict__ cre,
                                               const float* __restrict__ cim,
                                               float2* __restrict__ f)
{
    const int b   = blockIdx.x * blockDim.x + threadIdx.x;
    const int idx = blockIdx.y;                              // 0..120
    int l = (int)sqrtf((float)idx + 0.5f);
    if (l * l > idx) --l;
    if ((l + 1) * (l + 1) <= idx) ++l;
    const int j = idx - l * l;
    const int m = j - l;
    const float* crow  = cre + (size_t)b * 121 + l * 11;
    const float* cirow = cim + (size_t)b * 121 + l * 11;
    float re, im;
    if (m >= 0) { re = crow[m]; im = cirow[m]; }
    else {
        const int a = -m;
        const float sg = (a & 1) ? -1.0f : 1.0f;
        re = sg * crow[a]; im = -sg * cirow[a];
    }
    f[(size_t)idx * BATCH + b] = make_float2(re, im);
}

// ---------------------------------------------------------------------------
// Kernel 2: cg (fp32, [k][n] per pair) -> cg16 (f16, transposed [n][k],
// zero-padded to [nt*16][npan*32]). Same RNE conversion as round 5's stage B.
// ---------------------------------------------------------------------------
__global__ __launch_bounds__(256) void cg_to_f16(const float* __restrict__ cg,
                                                 short* __restrict__ cg16)
{
    int l1, l2, colbase, c16off; long long off;
    decode_pair_ext(blockIdx.y, l1, l2, off, colbase, c16off);
    const int d    = (2*l1+1)*(2*l2+1);
    const int lmin = l2 - l1;
    const int lmx  = (l1 + l2 < LMAX) ? (l1 + l2) : LMAX;
    const int used = (lmx+1)*(lmx+1) - lmin*lmin;
    const int npan = (d + 31) >> 5;
    const int nt   = (used + 15) >> 4;
    const int K32  = npan * 32;
    const int kbase = blockIdx.x * 64;
    if (kbase >= K32) return;
    const int kend  = (kbase + 64 < K32) ? kbase + 64 : K32;
    const int usedp = nt * 16;
    const int nn = threadIdx.x & 127;
    const int kh = threadIdx.x >> 7;
    if (nn >= usedp) return;
    for (int k = kbase + kh; k < kend; k += 2) {
        float v = 0.f;
        if (nn < used && k < d)
            v = cg[off + (size_t)k * d + nn];
        cg16[(size_t)c16off + (size_t)nn * K32 + k] = f32_to_f16_bits(v);
    }
}

// ---------------------------------------------------------------------------
// MFMA pair kernel — byte-identical to round 5 except stage B reads the
// pre-transposed f16 cg (vector copy) instead of 16 scalar loads + cvts.
// LDS: staging A_re[64][40] + A_im[64][40] + B_s[128][40] f16 (20.5 KB)
//      unioned with T[64][131] fp32 (33.5 KB).
// ---------------------------------------------------------------------------
template<int NT>
__device__ __forceinline__ void pair_body(const float2* __restrict__ f,
                                          const short* __restrict__ cg16,
                                          float* __restrict__ out,
                                          short* smem, int btile,
                                          int l1, int l2, int c16off, int colbase)
{
    const int d1 = 2*l1 + 1, d2 = 2*l2 + 1, d = d1 * d2;
    const int lmin = l2 - l1;
    const int lmx  = (l1 + l2 < LMAX) ? (l1 + l2) : LMAX;
    const int n_l  = lmx - lmin + 1;
    const int q1 = l1*l1, q2 = l2*l2;
    const int npan = (d + 31) >> 5;
    const int K32  = npan * 32;

    const int tid  = threadIdx.x;
    const int lane = tid & 63;
    const int w    = tid >> 6;        // wave 0..3 -> M-tile
    const int quad = lane >> 4;
    const int r16  = lane & 15;

    short* A_re = smem;               // [64][40] f16 bits
    short* A_im = smem + 64*40;
    short* B_s  = smem + 128*40;      // [128][40] f16 bits

    floatx4 accR[NT], accI[NT];
#pragma unroll
    for (int i = 0; i < NT; ++i) {
        accR[i] = (floatx4)0.0f; accI[i] = (floatx4)0.0f;
    }

    for (int pan = 0; pan < npan; ++pan) {
        const int k0 = pan << 5;

        // ---- stage A: tp[b, kk] = f1[b,m1] * f2[b,m2] (complex), f16 ----
        {
            const int mi = tid & 63;
            const int kq = tid >> 6;          // 8-wide k group
            const int b  = btile + mi;
            int kk = k0 + kq * 8;
            int m1 = kk / d2;
            int m2 = kk - m1 * d2;
            short8 vr, vi;
#pragma unroll
            for (int j = 0; j < 8; ++j) {
                float tr = 0.f, ti = 0.f;
                if (kk < d) {
                    const float2 a = f[(size_t)(q1 + m1) * BATCH + b];
                    const float2 c = f[(size_t)(q2 + m2) * BATCH + b];
                    tr = a.x * c.x - a.y * c.y;
                    ti = a.x * c.y + a.y * c.x;
                }
                vr[j] = f32_to_f16_bits(tr);
                vi[j] = f32_to_f16_bits(ti);
                ++kk;
                if (++m2 == d2) { m2 = 0; ++m1; }
            }
            *(short8*)&A_re[mi * 40 + kq * 8] = vr;
            *(short8*)&A_im[mi * 40 + kq * 8] = vi;
        }

        // ---- stage B: vector copy of pre-transposed f16 cg ----
        for (int ch = tid; ch < NT * 64; ch += 256) {
            const int n  = ch >> 2;           // cg column (B_s row), < NT*16
            const int cc = ch & 3;            // 16B chunk within 32-k panel
            const short8 v = *(const short8*)(cg16 + (size_t)c16off
                                              + (size_t)n * K32 + k0 + cc * 8);
            *(short8*)&B_s[n * 40 + cc * 8] = v;
        }
        __syncthreads();

        // ---- MFMA: A[m=lane&15][k=quad*8+j], B[k][n=lane&15] ----
        {
            const half8 are = __builtin_bit_cast(half8, *(const short8*)&A_re[(w*16 + r16) * 40 + quad * 8]);
            const half8 aim = __builtin_bit_cast(half8, *(const short8*)&A_im[(w*16 + r16) * 40 + quad * 8]);
#pragma unroll
            for (int n0 = 0; n0 < NT; ++n0) {
                const half8 bb = __builtin_bit_cast(half8, *(const short8*)&B_s[(n0*16 + r16) * 40 + quad * 8]);
                accR[n0] = __builtin_amdgcn_mfma_f32_16x16x32_f16(are, bb, accR[n0], 0, 0, 0);
                accI[n0] = __builtin_amdgcn_mfma_f32_16x16x32_f16(aim, bb, accI[n0], 0, 0, 0);
            }
        }
        __syncthreads();
    }

    // ---- two-pass fp32 epilogue; C/D: col=lane&15, row=quad*4+reg ----
    float* T = (float*)smem;                  // [64][131] fp32
    const int ntask = 64 * n_l;
    float part[3] = {0.f, 0.f, 0.f};

    // pass 1: real
#pragma unroll
    for (int n0 = 0; n0 < NT; ++n0)
#pragma unroll
        for (int r = 0; r < 4; ++r)
            T[(w*16 + quad*4 + r) * 131 + n0*16 + r16] = accR[n0][r];
    __syncthreads();
    {
        int it = 0;
        for (int task = tid; task < ntask; task += 256, ++it) {
            const int row = task & 63;
            const int li  = task >> 6;
            const int l   = lmin + li;
            const int sl  = l*l - lmin*lmin;
            const int W   = 2*l + 1;
            const int b   = btile + row;
            const float* Trow = T + row * 131 + sl;
            float acc = 0.f;
            for (int j = 0; j < W; ++j)
                acc = fmaf(Trow[j], f[(size_t)(l*l + j) * BATCH + b].x, acc);
            part[it] = acc;
        }
    }
    __syncthreads();

    // pass 2: imaginary
#pragma unroll
    for (int n0 = 0; n0 < NT; ++n0)
#pragma unroll
        for (int r = 0; r < 4; ++r)
            T[(w*16 + quad*4 + r) * 131 + n0*16 + r16] = accI[n0][r];
    __syncthreads();
    {
        int it = 0;
        for (int task = tid; task < ntask; task += 256, ++it) {
            const int row = task & 63;
            const int li  = task >> 6;
            const int l   = lmin + li;
            const int sl  = l*l - lmin*lmin;
            const int W   = 2*l + 1;
            const int b   = btile + row;
            const float* Trow = T + row * 131 + sl;
            float acc = part[it];
            for (int j = 0; j < W; ++j)
                acc = fmaf(Trow[j], f[(size_t)(l*l + j) * BATCH + b].y, acc);
            out[(size_t)b * NCOLS + colbase + li] = acc;
        }
    }
}

__global__ __launch_bounds__(256) void so3_mfma(const float2* __restrict__ f,
                                                const short* __restrict__ cg16,
                                                float* __restrict__ out)
{
    __shared__ __align__(16) short smem[16768];   // 33.5 KB
    const int btile = blockIdx.x * 64;
    const int p     = blockIdx.y;
    int l1, l2, colbase, c16off; long long off;
    decode_pair_ext(p, l1, l2, off, colbase, c16off);
    const int lmin = l2 - l1;
    const int lmx  = (l1 + l2 < LMAX) ? (l1 + l2) : LMAX;
    const int used = (lmx+1)*(lmx+1) - lmin*lmin;
    const int nt   = (used + 15) >> 4;
    switch (nt) {
        case 1: pair_body<1>(f, cg16, out, smem, btile, l1, l2, c16off, colbase); break;
        case 2: pair_body<2>(f, cg16, out, smem, btile, l1, l2, c16off, colbase); break;
        case 3: pair_body<3>(f, cg16, out, smem, btile, l1, l2, c16off, colbase); break;
        case 4: pair_body<4>(f, cg16, out, smem, btile, l1, l2, c16off, colbase); break;
        case 5: pair_body<5>(f, cg16, out, smem, btile, l1, l2, c16off, colbase); break;
        case 6: pair_body<6>(f, cg16, out, smem, btile, l1, l2, c16off, colbase); break;
        case 7: pair_body<7>(f, cg16, out, smem, btile, l1, l2, c16off, colbase); break;
        default: pair_body<8>(f, cg16, out, smem, btile, l1, l2, c16off, colbase); break;
    }
}

// ---------------------------------------------------------------------------
// Full fallback (fp32 VALU, no workspace). Round-5 copy.
// ---------------------------------------------------------------------------
template<int L>
__device__ __forceinline__ float core_fb(const float2* f1v, const float2* f2v,
                                         const float2* flv,
                                         const float* __restrict__ cgp,
                                         int d1, int d2, int d)
{
    constexpr int W = 2*L + 1;
    float accr[W], acci[W];
#pragma unroll
    for (int k = 0; k < W; ++k) { accr[k] = 0.f; acci[k] = 0.f; }
    for (int m1 = 0; m1 < d1; ++m1) {
        const float2 a = f1v[m1];
        const float* rowbase = cgp + (size_t)m1 * d2 * d;
        for (int m2 = 0; m2 < d2; ++m2) {
            const float2 bb = f2v[m2];
            const float tr = a.x*bb.x - a.y*bb.y;
            const float ti = a.x*bb.y + a.y*bb.x;
            const float* row = rowbase + (size_t)m2 * d;
#pragma unroll
            for (int k = 0; k < W; ++k) {
                accr[k] = fmaf(tr, row[k], accr[k]);
                acci[k] = fmaf(ti, row[k], acci[k]);
            }
        }
    }
    float orr = 0.f;
#pragma unroll
    for (int k = 0; k < W; ++k)
        orr = fmaf(accr[k], flv[k].x, fmaf(acci[k], flv[k].y, orr));
    return orr;
}

__global__ __launch_bounds__(256) void so3_tp_direct(const float* __restrict__ cre,
                                                     const float* __restrict__ cim,
                                                     const float* __restrict__ cg,
                                                     float* __restrict__ out)
{
    const int b = blockIdx.x * blockDim.x + threadIdx.x;
    const int t = blockIdx.y;
    int l1 = 0, l2 = 0, l = 0; long long off = 0;
    {
        int tt = t; long long o = 0;
        bool found = false;
        for (int a = 0; a <= LMAX && !found; ++a)
            for (int bq = a; bq <= LMAX && !found; ++bq) {
                const int d = (2*a+1)*(2*bq+1);
                const int lmin = bq - a;
                const int lmx = (a+bq < LMAX) ? (a+bq) : LMAX;
                const int cnt = lmx - lmin + 1;
                if (tt < cnt) { l1 = a; l2 = bq; l = lmin + tt; off = o; found = true; }
                else { tt -= cnt; o += (long long)d*d; }
            }
    }
    const int d1 = 2*l1+1, d2 = 2*l2+1, d = d1*d2;
    const int lmin = l2 - l1;
    const int s = l*l - lmin*lmin;

    const float* cr = cre + (size_t)b * 121;
    const float* ci = cim + (size_t)b * 121;
    float2 f1v[21], f2v[21], flv[21];
    for (int j = 0; j <= 2*l1; ++j) {
        const int m = j - l1;
        if (m >= 0) f1v[j] = make_float2(cr[l1*11+m], ci[l1*11+m]);
        else { const int a2 = -m; const float sg = (a2&1)?-1.f:1.f;
               f1v[j] = make_float2(sg*cr[l1*11+a2], -sg*ci[l1*11+a2]); }
    }
    for (int j = 0; j <= 2*l2; ++j) {
        const int m = j - l2;
        if (m >= 0) f2v[j] = make_float2(cr[l2*11+m], ci[l2*11+m]);
        else { const int a2 = -m; const float sg = (a2&1)?-1.f:1.f;
               f2v[j] = make_float2(sg*cr[l2*11+a2], -sg*ci[l2*11+a2]); }
    }
    for (int j = 0; j <= 2*l; ++j) {
        const int m = j - l;
        if (m >= 0) flv[j] = make_float2(cr[l*11+m], ci[l*11+m]);
        else { const int a2 = -m; const float sg = (a2&1)?-1.f:1.f;
               flv[j] = make_float2(sg*cr[l*11+a2], -sg*ci[l*11+a2]); }
    }
    const float* cgp = cg + off + s;
    float r;
    switch (l) {
        case 0: r = core_fb<0>(f1v,f2v,flv,cgp,d1,d2,d); break;
        case 1: r = core_fb<1>(f1v,f2v,flv,cgp,d1,d2,d); break;
        case 2: r = core_fb<2>(f1v,f2v,flv,cgp,d1,d2,d); break;
        case 3: r = core_fb<3>(f1v,f2v,flv,cgp,d1,d2,d); break;
        case 4: r = core_fb<4>(f1v,f2v,flv,cgp,d1,d2,d); break;
        case 5: r = core_fb<5>(f1v,f2v,flv,cgp,d1,d2,d); break;
        case 6: r = core_fb<6>(f1v,f2v,flv,cgp,d1,d2,d); break;
        case 7: r = core_fb<7>(f1v,f2v,flv,cgp,d1,d2,d); break;
        case 8: r = core_fb<8>(f1v,f2v,flv,cgp,d1,d2,d); break;
        case 9: r = core_fb<9>(f1v,f2v,flv,cgp,d1,d2,d); break;
        default: r = core_fb<10>(f1v,f2v,flv,cgp,d1,d2,d); break;
    }
    out[(size_t)b * NCOLS + t] = r;
}

// ---------------------------------------------------------------------------
extern "C" void kernel_launch(void* const* d_in, const int* in_sizes, int n_in,
                              void* d_out, int out_size, void* d_ws, size_t ws_size,
                              hipStream_t stream)
{
    const float* cre = (const float*)d_in[0];
    const float* cim = (const float*)d_in[1];
    const float* cg  = (const float*)d_in[2];
    float* out = (float*)d_out;

    // compute cg16 total size (same walk as decode_pair_ext)
    long long c16_total = 0;
    for (int l1 = 0; l1 <= LMAX; ++l1)
        for (int l2 = l1; l2 <= LMAX; ++l2) {
            const int d    = (2*l1+1)*(2*l2+1);
            const int lmin = l2 - l1;
            const int lmx  = (l1 + l2 < LMAX) ? (l1 + l2) : LMAX;
            const int used = (lmx+1)*(lmx+1) - lmin*lmin;
            c16_total += (long long)((used+15)/16) * 16 * ((d+31)/32) * 32;
        }

    const size_t f_bytes = (size_t)NF * BATCH * sizeof(float2);   // 15,859,712
    const size_t need    = f_bytes + (size_t)c16_total * 2;       // ~17.8 MB

    if (ws_size >= need) {
        float2* f    = (float2*)d_ws;
        short*  cg16 = (short*)((char*)d_ws + f_bytes);
        build_f  <<<dim3(BATCH/256, NF),     256, 0, stream>>>(cre, cim, f);
        cg_to_f16<<<dim3(7, NPAIRS),         256, 0, stream>>>(cg, cg16);
        so3_mfma <<<dim3(BATCH/64, NPAIRS),  256, 0, stream>>>(f, cg16, out);
    } else {
        so3_tp_direct<<<dim3(BATCH/256, NCOLS), 256, 0, stream>>>(cre, cim, cg, out);
    }
}

// Round 8
// 392.508 us; speedup vs baseline: 2.6362x; 1.1251x over previous
//
#include <hip/hip_runtime.h>

#define LMAX   10
#define BATCH  16384
#define NCOLS  381
#define NF     121
#define NPAIRS 66

typedef __attribute__((ext_vector_type(8))) short    short8;
typedef __attribute__((ext_vector_type(8))) _Float16 half8;
typedef __attribute__((ext_vector_type(2))) _Float16 half2v;
typedef __attribute__((ext_vector_type(4))) float    floatx4;

__device__ __forceinline__ short f32_to_f16_bits(float x) {
    return __builtin_bit_cast(short, (_Float16)x);   // RNE
}

// pair index p -> (l1, l2, cg offset, first output column, cg16 offset)
__device__ __forceinline__ void decode_pair_ext(int p, int& l1, int& l2,
                                                long long& off, int& colbase,
                                                int& c16off)
{
    long long o = 0; int cb = 0, c16 = 0, idx = 0;
    for (int a = 0; a <= LMAX; ++a) {
        for (int bq = a; bq <= LMAX; ++bq) {
            const int d    = (2*a+1)*(2*bq+1);
            const int lmin = bq - a;
            const int lmx  = (a + bq < LMAX) ? (a + bq) : LMAX;
            const int used = (lmx+1)*(lmx+1) - lmin*lmin;
            const int npan = (d + 31) >> 5;
            const int nt   = (used + 15) >> 4;
            if (idx == p) { l1 = a; l2 = bq; off = o; colbase = cb; c16off = c16; return; }
            o += (long long)d * d; cb += lmx - lmin + 1;
            c16 += nt * 16 * npan * 32; ++idx;
        }
    }
    l1 = l2 = 0; off = 0; colbase = 0; c16off = 0;
}

// ---------------------------------------------------------------------------
// Kernel 1: expand coeffs into f planes, layout (121, BATCH) float2 (fp32).
// Verified (rounds 3/5/7).
// ---------------------------------------------------------------------------
__global__ __launch_bounds__(256) void build_f(const float* __restrict__ cre,
                                               const float* __restrict__ cim,
                                               float2* __restrict__ f)
{
    const int b   = blockIdx.x * blockDim.x + threadIdx.x;
    const int idx = blockIdx.y;                              // 0..120
    int l = (int)sqrtf((float)idx + 0.5f);
    if (l * l > idx) --l;
    if ((l + 1) * (l + 1) <= idx) ++l;
    const int j = idx - l * l;
    const int m = j - l;
    const float* crow  = cre + (size_t)b * 121 + l * 11;
    const float* cirow = cim + (size_t)b * 121 + l * 11;
    float re, im;
    if (m >= 0) { re = crow[m]; im = cirow[m]; }
    else {
        const int a = -m;
        const float sg = (a & 1) ? -1.0f : 1.0f;
        re = sg * crow[a]; im = -sg * cirow[a];
    }
    f[(size_t)idx * BATCH + b] = make_float2(re, im);
}

// ---------------------------------------------------------------------------
// Kernel 2: cg (fp32, [k][n] per pair) -> cg16 (f16, transposed [n][k],
// zero-padded to [nt*16][npan*32]). Verified (round 7).
// ---------------------------------------------------------------------------
__global__ __launch_bounds__(256) void cg_to_f16(const float* __restrict__ cg,
                                                 short* __restrict__ cg16)
{
    int l1, l2, colbase, c16off; long long off;
    decode_pair_ext(blockIdx.y, l1, l2, off, colbase, c16off);
    const int d    = (2*l1+1)*(2*l2+1);
    const int lmin = l2 - l1;
    const int lmx  = (l1 + l2 < LMAX) ? (l1 + l2) : LMAX;
    const int used = (lmx+1)*(lmx+1) - lmin*lmin;
    const int npan = (d + 31) >> 5;
    const int nt   = (used + 15) >> 4;
    const int K32  = npan * 32;
    const int kbase = blockIdx.x * 64;
    if (kbase >= K32) return;
    const int kend  = (kbase + 64 < K32) ? kbase + 64 : K32;
    const int usedp = nt * 16;
    const int nn = threadIdx.x & 127;
    const int kh = threadIdx.x >> 7;
    if (nn >= usedp) return;
    for (int k = kbase + kh; k < kend; k += 2) {
        float v = 0.f;
        if (nn < used && k < d)
            v = cg[off + (size_t)k * d + nn];
        cg16[(size_t)c16off + (size_t)nn * K32 + k] = f32_to_f16_bits(v);
    }
}

// ---------------------------------------------------------------------------
// MFMA pair kernel — round 7 structure; ONE change: stage A reads per-block
// f16 LDS tiles (f12[(d1+d2)][64] packed half2, loaded once per block)
// instead of per-panel global f loads + f32 cmul + cvt.
// LDS union: staging A_re[64][40]+A_im[64][40]+B_s[128][40] (20.5 KB)
//            + f12 tiles (<=10.75 KB at offset 20.5 KB)  vs  T[64][131] fp32
//            (33.5 KB) -> block total 33.5 KB (unchanged from round 7).
// ---------------------------------------------------------------------------
template<int NT>
__device__ __forceinline__ void pair_body(const float2* __restrict__ f,
                                          const short* __restrict__ cg16,
                                          float* __restrict__ out,
                                          short* smem, int btile,
                                          int l1, int l2, int c16off, int colbase)
{
    const int d1 = 2*l1 + 1, d2 = 2*l2 + 1, d = d1 * d2;
    const int lmin = l2 - l1;
    const int lmx  = (l1 + l2 < LMAX) ? (l1 + l2) : LMAX;
    const int n_l  = lmx - lmin + 1;
    const int q1 = l1*l1, q2 = l2*l2;
    const int npan = (d + 31) >> 5;
    const int K32  = npan * 32;

    const int tid  = threadIdx.x;
    const int lane = tid & 63;
    const int w    = tid >> 6;        // wave 0..3 -> M-tile
    const int quad = lane >> 4;
    const int r16  = lane & 15;

    short* A_re = smem;               // [64][40] f16 bits
    short* A_im = smem + 64*40;
    short* B_s  = smem + 128*40;      // [128][40] f16 bits
    unsigned int* f12 = (unsigned int*)(smem + 10240);  // [(d1+d2)][64] half2

    // ---- load f1/f2 batch-tiles once, packed half2 {re, im} ----
    {
        const int nmm = (d1 + d2) * 64;
        for (int t2 = tid; t2 < nmm; t2 += 256) {
            const int m   = t2 >> 6;
            const int mi2 = t2 & 63;
            const float2 v = (m < d1)
                ? f[(size_t)(q1 + m)      * BATCH + btile + mi2]
                : f[(size_t)(q2 + m - d1) * BATCH + btile + mi2];
            half2v h; h.x = (_Float16)v.x; h.y = (_Float16)v.y;
            f12[t2] = __builtin_bit_cast(unsigned int, h);
        }
    }
    __syncthreads();

    floatx4 accR[NT], accI[NT];
#pragma unroll
    for (int i = 0; i < NT; ++i) {
        accR[i] = (floatx4)0.0f; accI[i] = (floatx4)0.0f;
    }

    const int mi = tid & 63;          // staging: batch row
    const int kq = tid >> 6;          // staging: 8-wide k group

    for (int pan = 0; pan < npan; ++pan) {
        const int k0 = pan << 5;

        // ---- stage A: tp[b, kk] = f1[b,m1] * f2[b,m2] (complex, f16) ----
        {
            int kk = k0 + kq * 8;
            int m1 = kk / d2;
            int m2 = kk - m1 * d2;
            short8 vr, vi;
#pragma unroll
            for (int j = 0; j < 8; ++j) {
                _Float16 tr = (_Float16)0.f, ti = (_Float16)0.f;
                if (kk < d) {
                    const half2v a = __builtin_bit_cast(half2v, f12[m1 * 64 + mi]);
                    const half2v c = __builtin_bit_cast(half2v, f12[(d1 + m2) * 64 + mi]);
                    tr = a.x * c.x - a.y * c.y;
                    ti = a.x * c.y + a.y * c.x;
                }
                vr[j] = __builtin_bit_cast(short, tr);
                vi[j] = __builtin_bit_cast(short, ti);
                ++kk;
                if (++m2 == d2) { m2 = 0; ++m1; }
            }
            *(short8*)&A_re[mi * 40 + kq * 8] = vr;
            *(short8*)&A_im[mi * 40 + kq * 8] = vi;
        }

        // ---- stage B: vector copy of pre-transposed f16 cg ----
        for (int ch = tid; ch < NT * 64; ch += 256) {
            const int n  = ch >> 2;           // cg column (B_s row), < NT*16
            const int cc = ch & 3;            // 16B chunk within 32-k panel
            const short8 v = *(const short8*)(cg16 + (size_t)c16off
                                              + (size_t)n * K32 + k0 + cc * 8);
            *(short8*)&B_s[n * 40 + cc * 8] = v;
        }
        __syncthreads();

        // ---- MFMA: A[m=lane&15][k=quad*8+j], B[k][n=lane&15] ----
        {
            const half8 are = __builtin_bit_cast(half8, *(const short8*)&A_re[(w*16 + r16) * 40 + quad * 8]);
            const half8 aim = __builtin_bit_cast(half8, *(const short8*)&A_im[(w*16 + r16) * 40 + quad * 8]);
#pragma unroll
            for (int n0 = 0; n0 < NT; ++n0) {
                const half8 bb = __builtin_bit_cast(half8, *(const short8*)&B_s[(n0*16 + r16) * 40 + quad * 8]);
                accR[n0] = __builtin_amdgcn_mfma_f32_16x16x32_f16(are, bb, accR[n0], 0, 0, 0);
                accI[n0] = __builtin_amdgcn_mfma_f32_16x16x32_f16(aim, bb, accI[n0], 0, 0, 0);
            }
        }
        __syncthreads();
    }

    // ---- two-pass fp32 epilogue; C/D: col=lane&15, row=quad*4+reg ----
    float* T = (float*)smem;                  // [64][131] fp32 (overlaps all)
    const int ntask = 64 * n_l;
    float part[3] = {0.f, 0.f, 0.f};

    // pass 1: real
#pragma unroll
    for (int n0 = 0; n0 < NT; ++n0)
#pragma unroll
        for (int r = 0; r < 4; ++r)
            T[(w*16 + quad*4 + r) * 131 + n0*16 + r16] = accR[n0][r];
    __syncthreads();
    {
        int it = 0;
        for (int task = tid; task < ntask; task += 256, ++it) {
            const int row = task & 63;
            const int li  = task >> 6;
            const int l   = lmin + li;
            const int sl  = l*l - lmin*lmin;
            const int W   = 2*l + 1;
            const int b   = btile + row;
            const float* Trow = T + row * 131 + sl;
            float acc = 0.f;
            for (int j = 0; j < W; ++j)
                acc = fmaf(Trow[j], f[(size_t)(l*l + j) * BATCH + b].x, acc);
            part[it] = acc;
        }
    }
    __syncthreads();

    // pass 2: imaginary
#pragma unroll
    for (int n0 = 0; n0 < NT; ++n0)
#pragma unroll
        for (int r = 0; r < 4; ++r)
            T[(w*16 + quad*4 + r) * 131 + n0*16 + r16] = accI[n0][r];
    __syncthreads();
    {
        int it = 0;
        for (int task = tid; task < ntask; task += 256, ++it) {
            const int row = task & 63;
            const int li  = task >> 6;
            const int l   = lmin + li;
            const int sl  = l*l - lmin*lmin;
            const int W   = 2*l + 1;
            const int b   = btile + row;
            const float* Trow = T + row * 131 + sl;
            float acc = part[it];
            for (int j = 0; j < W; ++j)
                acc = fmaf(Trow[j], f[(size_t)(l*l + j) * BATCH + b].y, acc);
            out[(size_t)b * NCOLS + colbase + li] = acc;
        }
    }
}

__global__ __launch_bounds__(256) void so3_mfma(const float2* __restrict__ f,
                                                const short* __restrict__ cg16,
                                                float* __restrict__ out)
{
    __shared__ __align__(16) short smem[16768];   // 33.5 KB
    const int btile = blockIdx.x * 64;
    const int p     = blockIdx.y;
    int l1, l2, colbase, c16off; long long off;
    decode_pair_ext(p, l1, l2, off, colbase, c16off);
    const int lmin = l2 - l1;
    const int lmx  = (l1 + l2 < LMAX) ? (l1 + l2) : LMAX;
    const int used = (lmx+1)*(lmx+1) - lmin*lmin;
    const int nt   = (used + 15) >> 4;
    switch (nt) {
        case 1: pair_body<1>(f, cg16, out, smem, btile, l1, l2, c16off, colbase); break;
        case 2: pair_body<2>(f, cg16, out, smem, btile, l1, l2, c16off, colbase); break;
        case 3: pair_body<3>(f, cg16, out, smem, btile, l1, l2, c16off, colbase); break;
        case 4: pair_body<4>(f, cg16, out, smem, btile, l1, l2, c16off, colbase); break;
        case 5: pair_body<5>(f, cg16, out, smem, btile, l1, l2, c16off, colbase); break;
        case 6: pair_body<6>(f, cg16, out, smem, btile, l1, l2, c16off, colbase); break;
        case 7: pair_body<7>(f, cg16, out, smem, btile, l1, l2, c16off, colbase); break;
        default: pair_body<8>(f, cg16, out, smem, btile, l1, l2, c16off, colbase); break;
    }
}

// ---------------------------------------------------------------------------
// Full fallback (fp32 VALU, no workspace). Round-5 copy.
// ---------------------------------------------------------------------------
template<int L>
__device__ __forceinline__ float core_fb(const float2* f1v, const float2* f2v,
                                         const float2* flv,
                                         const float* __restrict__ cgp,
                                         int d1, int d2, int d)
{
    constexpr int W = 2*L + 1;
    float accr[W], acci[W];
#pragma unroll
    for (int k = 0; k < W; ++k) { accr[k] = 0.f; acci[k] = 0.f; }
    for (int m1 = 0; m1 < d1; ++m1) {
        const float2 a = f1v[m1];
        const float* rowbase = cgp + (size_t)m1 * d2 * d;
        for (int m2 = 0; m2 < d2; ++m2) {
            const float2 bb = f2v[m2];
            const float tr = a.x*bb.x - a.y*bb.y;
            const float ti = a.x*bb.y + a.y*bb.x;
            const float* row = rowbase + (size_t)m2 * d;
#pragma unroll
            for (int k = 0; k < W; ++k) {
                accr[k] = fmaf(tr, row[k], accr[k]);
                acci[k] = fmaf(ti, row[k], acci[k]);
            }
        }
    }
    float orr = 0.f;
#pragma unroll
    for (int k = 0; k < W; ++k)
        orr = fmaf(accr[k], flv[k].x, fmaf(acci[k], flv[k].y, orr));
    return orr;
}

__global__ __launch_bounds__(256) void so3_tp_direct(const float* __restrict__ cre,
                                                     const float* __restrict__ cim,
                                                     const float* __restrict__ cg,
                                                     float* __restrict__ out)
{
    const int b = blockIdx.x * blockDim.x + threadIdx.x;
    const int t = blockIdx.y;
    int l1 = 0, l2 = 0, l = 0; long long off = 0;
    {
        int tt = t; long long o = 0;
        bool found = false;
        for (int a = 0; a <= LMAX && !found; ++a)
            for (int bq = a; bq <= LMAX && !found; ++bq) {
                const int d = (2*a+1)*(2*bq+1);
                const int lmin = bq - a;
                const int lmx = (a+bq < LMAX) ? (a+bq) : LMAX;
                const int cnt = lmx - lmin + 1;
                if (tt < cnt) { l1 = a; l2 = bq; l = lmin + tt; off = o; found = true; }
                else { tt -= cnt; o += (long long)d*d; }
            }
    }
    const int d1 = 2*l1+1, d2 = 2*l2+1, d = d1*d2;
    const int lmin = l2 - l1;
    const int s = l*l - lmin*lmin;

    const float* cr = cre + (size_t)b * 121;
    const float* ci = cim + (size_t)b * 121;
    float2 f1v[21], f2v[21], flv[21];
    for (int j = 0; j <= 2*l1; ++j) {
        const int m = j - l1;
        if (m >= 0) f1v[j] = make_float2(cr[l1*11+m], ci[l1*11+m]);
        else { const int a2 = -m; const float sg = (a2&1)?-1.f:1.f;
               f1v[j] = make_float2(sg*cr[l1*11+a2], -sg*ci[l1*11+a2]); }
    }
    for (int j = 0; j <= 2*l2; ++j) {
        const int m = j - l2;
        if (m >= 0) f2v[j] = make_float2(cr[l2*11+m], ci[l2*11+m]);
        else { const int a2 = -m; const float sg = (a2&1)?-1.f:1.f;
               f2v[j] = make_float2(sg*cr[l2*11+a2], -sg*ci[l2*11+a2]); }
    }
    for (int j = 0; j <= 2*l; ++j) {
        const int m = j - l;
        if (m >= 0) flv[j] = make_float2(cr[l*11+m], ci[l*11+m]);
        else { const int a2 = -m; const float sg = (a2&1)?-1.f:1.f;
               flv[j] = make_float2(sg*cr[l*11+a2], -sg*ci[l*11+a2]); }
    }
    const float* cgp = cg + off + s;
    float r;
    switch (l) {
        case 0: r = core_fb<0>(f1v,f2v,flv,cgp,d1,d2,d); break;
        case 1: r = core_fb<1>(f1v,f2v,flv,cgp,d1,d2,d); break;
        case 2: r = core_fb<2>(f1v,f2v,flv,cgp,d1,d2,d); break;
        case 3: r = core_fb<3>(f1v,f2v,flv,cgp,d1,d2,d); break;
        case 4: r = core_fb<4>(f1v,f2v,flv,cgp,d1,d2,d); break;
        case 5: r = core_fb<5>(f1v,f2v,flv,cgp,d1,d2,d); break;
        case 6: r = core_fb<6>(f1v,f2v,flv,cgp,d1,d2,d); break;
        case 7: r = core_fb<7>(f1v,f2v,flv,cgp,d1,d2,d); break;
        case 8: r = core_fb<8>(f1v,f2v,flv,cgp,d1,d2,d); break;
        case 9: r = core_fb<9>(f1v,f2v,flv,cgp,d1,d2,d); break;
        default: r = core_fb<10>(f1v,f2v,flv,cgp,d1,d2,d); break;
    }
    out[(size_t)b * NCOLS + t] = r;
}

// ---------------------------------------------------------------------------
extern "C" void kernel_launch(void* const* d_in, const int* in_sizes, int n_in,
                              void* d_out, int out_size, void* d_ws, size_t ws_size,
                              hipStream_t stream)
{
    const float* cre = (const float*)d_in[0];
    const float* cim = (const float*)d_in[1];
    const float* cg  = (const float*)d_in[2];
    float* out = (float*)d_out;

    // compute cg16 total size (same walk as decode_pair_ext)
    long long c16_total = 0;
    for (int l1 = 0; l1 <= LMAX; ++l1)
        for (int l2 = l1; l2 <= LMAX; ++l2) {
            const int d    = (2*l1+1)*(2*l2+1);
            const int lmin = l2 - l1;
            const int lmx  = (l1 + l2 < LMAX) ? (l1 + l2) : LMAX;
            const int used = (lmx+1)*(lmx+1) - lmin*lmin;
            c16_total += (long long)((used+15)/16) * 16 * ((d+31)/32) * 32;
        }

    const size_t f_bytes = (size_t)NF * BATCH * sizeof(float2);   // 15,859,712
    const size_t need    = f_bytes + (size_t)c16_total * 2;       // ~17.8 MB

    if (ws_size >= need) {
        float2* f    = (float2*)d_ws;
        short*  cg16 = (short*)((char*)d_ws + f_bytes);
        build_f  <<<dim3(BATCH/256, NF),     256, 0, stream>>>(cre, cim, f);
        cg_to_f16<<<dim3(7, NPAIRS),         256, 0, stream>>>(cg, cg16);
        so3_mfma <<<dim3(BATCH/64, NPAIRS),  256, 0, stream>>>(f, cg16, out);
    } else {
        so3_tp_direct<<<dim3(BATCH/256, NCOLS), 256, 0, stream>>>(cre, cim, cg, out);
    }
}